// Round 1
// baseline (59.428 us; speedup 1.0000x reference)
//
#include <hip/hip_runtime.h>

// out[i] = weight[i] * dot(x, x0) + bias[i] + x[i],  D = 8192, all fp32.
// outer(w,x) @ x0 == w * (x . x0) -- no [D,D] matrix needed.
//
// D = 8192 = 1024 threads * 2 float4 * 4 floats. Single block: the whole
// problem is 192 KB of traffic; launch latency dominates, so one launch,
// no workspace, no atomics.

#define D 8192
#define NTHREADS 1024

__global__ __launch_bounds__(NTHREADS) void cross_layer_kernel(
    const float* __restrict__ x0,
    const float* __restrict__ x,
    const float* __restrict__ weight,
    const float* __restrict__ bias,
    float* __restrict__ out) {

    const int tid = threadIdx.x;

    const float4* __restrict__ x04 = (const float4*)x0;
    const float4* __restrict__ x4  = (const float4*)x;
    const float4* __restrict__ w4  = (const float4*)weight;
    const float4* __restrict__ b4  = (const float4*)bias;
    float4* __restrict__ o4        = (float4*)out;

    // ---- Phase 1: dot(x, x0) ----
    // Each thread covers float4 indices tid and tid+1024 (2048 float4 total).
    float4 xa0 = x04[tid];
    float4 xa1 = x04[tid + NTHREADS];
    float4 xb0 = x4[tid];
    float4 xb1 = x4[tid + NTHREADS];

    float p = xa0.x * xb0.x + xa0.y * xb0.y + xa0.z * xb0.z + xa0.w * xb0.w
            + xa1.x * xb1.x + xa1.y * xb1.y + xa1.z * xb1.z + xa1.w * xb1.w;

    // Wave-64 shuffle reduction.
    #pragma unroll
    for (int off = 32; off > 0; off >>= 1) {
        p += __shfl_down(p, off, 64);
    }

    __shared__ float s_wave[NTHREADS / 64];
    __shared__ float s_dot;
    const int lane = tid & 63;
    const int wave = tid >> 6;
    if (lane == 0) s_wave[wave] = p;
    __syncthreads();

    if (tid == 0) {
        float d = 0.0f;
        #pragma unroll
        for (int i = 0; i < NTHREADS / 64; ++i) d += s_wave[i];
        s_dot = d;
    }
    __syncthreads();
    const float dot = s_dot;

    // ---- Phase 2: elementwise epilogue (x values already in registers) ----
    float4 wv0 = w4[tid];
    float4 wv1 = w4[tid + NTHREADS];
    float4 bv0 = b4[tid];
    float4 bv1 = b4[tid + NTHREADS];

    float4 r0, r1;
    r0.x = fmaf(wv0.x, dot, bv0.x + xb0.x);
    r0.y = fmaf(wv0.y, dot, bv0.y + xb0.y);
    r0.z = fmaf(wv0.z, dot, bv0.z + xb0.z);
    r0.w = fmaf(wv0.w, dot, bv0.w + xb0.w);
    r1.x = fmaf(wv1.x, dot, bv1.x + xb1.x);
    r1.y = fmaf(wv1.y, dot, bv1.y + xb1.y);
    r1.z = fmaf(wv1.z, dot, bv1.z + xb1.z);
    r1.w = fmaf(wv1.w, dot, bv1.w + xb1.w);

    o4[tid] = r0;
    o4[tid + NTHREADS] = r1;
}

extern "C" void kernel_launch(void* const* d_in, const int* in_sizes, int n_in,
                              void* d_out, int out_size, void* d_ws, size_t ws_size,
                              hipStream_t stream) {
    const float* x0     = (const float*)d_in[0];
    const float* x      = (const float*)d_in[1];
    const float* weight = (const float*)d_in[2];
    const float* bias   = (const float*)d_in[3];
    float* out          = (float*)d_out;

    cross_layer_kernel<<<1, NTHREADS, 0, stream>>>(x0, x, weight, bias, out);
}

// Round 2
// 59.418 us; speedup vs baseline: 1.0002x; 1.0002x over previous
//
#include <hip/hip_runtime.h>

// out[i] = weight[i] * dot(x, x0) + bias[i] + x[i],  D = 8192, all fp32.
// outer(w,x) @ x0 == w * (x . x0) -- the [D,D] matrix is never needed.
//
// Strategy: 32 blocks x 256 threads. EVERY block redundantly computes the
// full dot(x, x0) (64 KB of reads per block -- shared via L2/L3, trivial),
// so there is no grid-wide reduction, no atomics, no multi-kernel
// serialization. Each block then writes its own 256-element output slice.
// This spreads the latency-bound work over 32 CUs instead of 1.

#define D 8192
#define NTHREADS 256
#define NBLOCKS (D / NTHREADS)      // 32
#define F4_PER_THREAD ((D / 4) / NTHREADS)  // 8

__global__ __launch_bounds__(NTHREADS) void cross_layer_kernel(
    const float* __restrict__ x0,
    const float* __restrict__ x,
    const float* __restrict__ weight,
    const float* __restrict__ bias,
    float* __restrict__ out) {

    const int tid = threadIdx.x;
    const int gid = blockIdx.x * NTHREADS + tid;

    const float4* __restrict__ x04 = (const float4*)x0;
    const float4* __restrict__ x4  = (const float4*)x;

    // ---- Phase 1 loads: full x, x0 (redundant per block) ----
    float4 a[F4_PER_THREAD];
    float4 b[F4_PER_THREAD];
    #pragma unroll
    for (int k = 0; k < F4_PER_THREAD; ++k) {
        a[k] = x04[tid + k * NTHREADS];
        b[k] = x4[tid + k * NTHREADS];
    }

    // Prefetch epilogue operands now so their latency hides under the
    // reduction below.
    const float wi = weight[gid];
    const float bi = bias[gid];
    const float xi = x[gid];

    float p = 0.0f;
    #pragma unroll
    for (int k = 0; k < F4_PER_THREAD; ++k) {
        p += a[k].x * b[k].x + a[k].y * b[k].y
           + a[k].z * b[k].z + a[k].w * b[k].w;
    }

    // ---- Wave-64 shuffle reduction, then tiny LDS combine (4 waves) ----
    #pragma unroll
    for (int off = 32; off > 0; off >>= 1) {
        p += __shfl_down(p, off, 64);
    }

    __shared__ float s_wave[NTHREADS / 64];
    __shared__ float s_dot;
    const int lane = tid & 63;
    const int wave = tid >> 6;
    if (lane == 0) s_wave[wave] = p;
    __syncthreads();
    if (tid == 0) {
        s_dot = s_wave[0] + s_wave[1] + s_wave[2] + s_wave[3];
    }
    __syncthreads();
    const float dot = s_dot;

    // ---- Epilogue: this block's 256-element slice ----
    out[gid] = fmaf(wi, dot, bi + xi);
}

extern "C" void kernel_launch(void* const* d_in, const int* in_sizes, int n_in,
                              void* d_out, int out_size, void* d_ws, size_t ws_size,
                              hipStream_t stream) {
    const float* x0     = (const float*)d_in[0];
    const float* x      = (const float*)d_in[1];
    const float* weight = (const float*)d_in[2];
    const float* bias   = (const float*)d_in[3];
    float* out          = (float*)d_out;

    cross_layer_kernel<<<NBLOCKS, NTHREADS, 0, stream>>>(x0, x, weight, bias, out);
}